// Round 12
// baseline (115.375 us; speedup 1.0000x reference)
//
#include <hip/hip_runtime.h>

typedef unsigned long long u64;

#define L_DIM 4096
#define B_DIM 4
#define KNN 48
#define CAP 256             // survivors/row ~50 expected (F~1.2%); 5x margin
#define INVALID_X2 1.0e30f  // encodes mask=0: d^2 ~ 1e30, never selectable
#define VALID_TH 1.0e29f
#define SLACK 8u            // ulp slack on d^2 threshold covering sqrt collisions
#define NT 512              // threads/block
#define NW 8                // waves/block
#define CPT 8               // candidates per thread (NT*CPT = L_DIM)
#define ROWS 4              // query rows per block (same batch; candidates shared)

// ---------------------------------------------------------------------------
// prep: c4 = (x, y, z, valid ? x2 : 1e30). No atomics, no side arrays.
// x2 contracted-FMA chain (matches XLA:CPU fused codegen); dot(i,i) == x2(i)
// bit-exact => D[i,i] == 0 exactly.
// ---------------------------------------------------------------------------
__global__ __launch_bounds__(256) void prep_kernel(const float* __restrict__ X,
                                                   const float* __restrict__ mask,
                                                   float4* __restrict__ c4) {
#pragma clang fp contract(off)
    int i = blockIdx.x * 256 + threadIdx.x;              // i in [0, B*L)
    const float4* X4 = (const float4*)X;                 // residue = 3 aligned float4
    float4 a = X4[3 * i];                                // ... f3(=CA x)
    float4 bb = X4[3 * i + 1];                           // f4(=CA y) f5(=CA z) ...
    float x = a.w, y = bb.x, z = bb.y;
    float x2 = __builtin_fmaf(z, z, __builtin_fmaf(y, y, x * x));
    float m = mask[i];
    c4[i] = make_float4(x, y, z, (m > 0.0f) ? x2 : INVALID_X2);
}

// full ascending 64-lane bitonic sort; returns this lane's sorted value
__device__ __forceinline__ unsigned wave_sort64(unsigned sv, int lane) {
#pragma unroll
    for (int k = 2; k <= 64; k <<= 1) {
#pragma unroll
        for (int j = k >> 1; j > 0; j >>= 1) {
            unsigned o = __shfl_xor(sv, j);
            unsigned mn = min(sv, o), mx = max(sv, o);
            bool asc = ((lane & k) == 0);
            bool low = ((lane & j) == 0);
            sv = (asc == low) ? mn : mx;
        }
    }
    return sv;
}

// ---------------------------------------------------------------------------
// main: one block per 4 consecutive rows (same batch), 512 threads.
//  A:  load 8 candidates ONCE; d^2 bits for ALL 4 rows; per-row per-thread
//      min; candidate-validity count for n_valid.
//  A': block reduce n_valid; degenerate batch -> self-fill all rows.
//  B:  certified tight threshold per row = EXACT 48th-smallest of the 512
//      thread-minima (<=47 elements < q48 => <=47 minima < q48 => 48th
//      minimum >= q48; tightness: 1-(1-F)^8 = 48/512 => F~1.2% => S~50).
//      Impl: per-wave bitonic sort -> composite (val,id) lists in LDS ->
//      first-48-of-each-list rank via 7 binary searches; rank-47 publishes T.
//  C:  compact survivors (d2 <= T+SLACK; SLACK covers sqrt-collision ties),
//      storing EXACT key (sqrt_bits<<32|j) at push time.
//  D:  rank-count in (sqrt_bits, idx) order == lax.top_k tie-break, scatter;
//      invalid row -> self-fill. All cross-stage LDS deps barriered (4 total).
// ---------------------------------------------------------------------------
__global__ __launch_bounds__(NT) void knn_kernel(const float4* __restrict__ c4,
                                                 float* __restrict__ dn,
                                                 float* __restrict__ ei) {
    __shared__ u64 smin[ROWS][NT];      // 16 KB: sorted minima (composite keys)
    __shared__ u64 surv[ROWS][CAP];     //  8 KB
    __shared__ int nvw[NW];
    __shared__ int cnt[ROWS];
    __shared__ unsigned Tsh[ROWS];

    const int row0 = blockIdx.x * ROWS;
    const int b = row0 >> 12;
    const int i0 = row0 & (L_DIM - 1);
    const int t = threadIdx.x;
    const int w = t >> 6, lane = t & 63;

    const float4* cb = c4 + (size_t)b * L_DIM;
    float4 q[ROWS];
    bool vq[ROWS];
#pragma unroll
    for (int r = 0; r < ROWS; ++r) {
        q[r] = cb[i0 + r];                     // broadcast loads
        vq[r] = (q[r].w < VALID_TH);
    }

    // ---- A: 8 candidates/thread, d^2 for 4 rows + validity count ----
    unsigned d2[ROWS][CPT];
    unsigned rmin[ROWS];
#pragma unroll
    for (int r = 0; r < ROWS; ++r) rmin[r] = 0xFFFFFFFFu;
    int nvt = 0;
    {
#pragma clang fp contract(off)
#pragma unroll
        for (int c = 0; c < CPT; ++c) {
            int j = c * NT + t;
            float4 pj = cb[j];
            nvt += (pj.w < VALID_TH) ? 1 : 0;
#pragma unroll
            for (int r = 0; r < ROWS; ++r) {
                float dot = __builtin_fmaf(pj.z, q[r].z,
                            __builtin_fmaf(pj.y, q[r].y, pj.x * q[r].x));
                // fma(-2,dot,t1) == (t1 - 2*dot) bit-exact (2*dot exact, 1 rnd)
                float d2v = fmaxf(__builtin_fmaf(-2.0f, dot, q[r].w + pj.w), 0.0f);
                d2[r][c] = __float_as_uint(d2v);
                rmin[r] = min(rmin[r], d2[r][c]);
            }
        }
    }

    // ---- A': n_valid block reduce; degen -> self-fill all rows ----
#pragma unroll
    for (int s = 1; s < 64; s <<= 1) nvt += __shfl_xor(nvt, s);
    if (lane == 0) nvw[w] = nvt;
    if (t < ROWS) cnt[t] = 0;
    __syncthreads();                                   // S1
    {
        int nv = 0;
#pragma unroll
        for (int k = 0; k < NW; ++k) nv += nvw[k];
        if (nv <= KNN) {
            if (w < ROWS && lane < KNN) {
                dn[(size_t)(row0 + w) * KNN + lane] = 0.0f;
                ei[(size_t)(row0 + w) * KNN + lane] = (float)(i0 + w);
            }
            return;
        }
    }

    // ---- B: sorted minima lists (composite (value<<32)|uniqueid) ----
#pragma unroll
    for (int r = 0; r < ROWS; ++r) {
        unsigned sv = wave_sort64(rmin[r], lane);
        smin[r][t] = ((u64)sv << 32) | (unsigned)t;    // ascending per wave seg
    }
    __syncthreads();                                   // S2

    // rank-search: candidates = first KNN of each wave's sorted list, all rows
    for (int tau = t; tau < ROWS * NW * KNN; tau += NT) {
        int r = tau / (NW * KNN);
        int rest = tau - r * (NW * KNN);
        int ww = rest / KNN, p = rest - ww * KNN;
        u64 key = smin[r][ww * 64 + p];
        int grank = p;                          // elements before it in own list
#pragma unroll
        for (int w2 = 0; w2 < NW; ++w2) {
            if (w2 == ww) continue;
            const u64* arr = &smin[r][w2 * 64];
            int lo = 0;
#pragma unroll
            for (int s = 32; s >= 1; s >>= 1)
                if (arr[lo + s - 1] < key) lo += s;
            lo += (arr[lo] < key) ? 1 : 0;      // lo in [0,64] = count < key
            grank += lo;
        }
        if (grank == KNN - 1) Tsh[r] = (unsigned)(key >> 32);  // unique publisher
    }
    __syncthreads();                                   // S3
    unsigned Tp[ROWS];
#pragma unroll
    for (int r = 0; r < ROWS; ++r) Tp[r] = vq[r] ? (Tsh[r] + SLACK) : 0u;

    // ---- C: compact survivors per row, exact sqrt key at push time ----
#pragma unroll
    for (int c = 0; c < CPT; ++c) {
        unsigned j = (unsigned)(c * NT + t);
#pragma unroll
        for (int r = 0; r < ROWS; ++r) {
            if (d2[r][c] <= Tp[r]) {
                int pos = atomicAdd(&cnt[r], 1);
                if (pos < CAP) {
                    float d = sqrtf(__uint_as_float(d2[r][c]));  // correctly rnd
                    surv[r][pos] = ((u64)__float_as_uint(d) << 32) | j;
                }
            }
        }
    }
    __syncthreads();                                   // S4

    // ---- D: per row, block-wide exact rank + scatter (or self-fill) ----
#pragma unroll
    for (int r = 0; r < ROWS; ++r) {
        float* dnrow = dn + (size_t)(row0 + r) * KNN;
        float* eirow = ei + (size_t)(row0 + r) * KNN;
        if (!vq[r]) {                           // block-uniform branch
            if (t < KNN) { dnrow[t] = 0.0f; eirow[t] = (float)(i0 + r); }
        } else {
            int S = cnt[r]; if (S > CAP) S = CAP;
            for (int c = t; c < S; c += NT) {
                u64 key = surv[r][c];
                int rank = 0;
                for (int s = 0; s < S; ++s) rank += (surv[r][s] < key);  // bcast
                if (rank < KNN) {
                    dnrow[rank] = __uint_as_float((unsigned)(key >> 32));
                    eirow[rank] = (float)(key & 0xFFFFFFFFULL);
                }
            }
        }
    }
}

extern "C" void kernel_launch(void* const* d_in, const int* in_sizes, int n_in,
                              void* d_out, int out_size, void* d_ws, size_t ws_size,
                              hipStream_t stream) {
    const float* X = (const float*)d_in[0];
    const float* mask = (const float*)d_in[1];

    float* out = (float*)d_out;
    float* dn = out;                                   // (B,L,K) D_neighbors
    float* ei = out + (size_t)B_DIM * L_DIM * KNN;     // (B,L,K) E_idx as f32

    float4* c4 = (float4*)d_ws;                        // 256 KiB scratch

    prep_kernel<<<(B_DIM * L_DIM) / 256, 256, 0, stream>>>(X, mask, c4);
    knn_kernel<<<(B_DIM * L_DIM) / ROWS, NT, 0, stream>>>(c4, dn, ei);
}

// Round 13
// 91.413 us; speedup vs baseline: 1.2621x; 1.2621x over previous
//
#include <hip/hip_runtime.h>

typedef unsigned long long u64;
typedef float v2f __attribute__((ext_vector_type(2)));

#define L_DIM 4096
#define B_DIM 4
#define KNN 48
#define CAP 512             // survivors/row ~55 measured; 9x margin
#define INVALID_X2 1.0e30f  // encodes mask=0: d^2 ~ 1e30, never selectable
#define VALID_TH 1.0e29f
#define SLACK 8u            // ulp slack on d^2 threshold covering sqrt collisions
#define NT 256
#define NW 4
#define CPT 16              // candidates per thread (NT*CPT = L_DIM)
#define ROWS 2              // query rows per block (packed into v2f lanes)

// packed helpers: bit-identical per half to the scalar ops (IEEE fma/max/min)
#if __has_builtin(__builtin_elementwise_fma)
__device__ __forceinline__ v2f vfma2(v2f a, v2f b, v2f c) {
    return __builtin_elementwise_fma(a, b, c);
}
#else
__device__ __forceinline__ v2f vfma2(v2f a, v2f b, v2f c) {
    v2f r; r.x = __builtin_fmaf(a.x, b.x, c.x); r.y = __builtin_fmaf(a.y, b.y, c.y);
    return r;
}
#endif
#if __has_builtin(__builtin_elementwise_max)
__device__ __forceinline__ v2f vmax2(v2f a, v2f b) { return __builtin_elementwise_max(a, b); }
#else
__device__ __forceinline__ v2f vmax2(v2f a, v2f b) {
    v2f r; r.x = fmaxf(a.x, b.x); r.y = fmaxf(a.y, b.y); return r;
}
#endif
#if __has_builtin(__builtin_elementwise_min)
__device__ __forceinline__ v2f vmin2(v2f a, v2f b) { return __builtin_elementwise_min(a, b); }
#else
__device__ __forceinline__ v2f vmin2(v2f a, v2f b) {
    v2f r; r.x = fminf(a.x, b.x); r.y = fminf(a.y, b.y); return r;
}
#endif

// ---------------------------------------------------------------------------
// prep: c4 = (x, y, z, valid ? x2 : 1e30); per-batch n_valid via one ballot +
// lane0 atomic per wave (single-address, coalesced-friendly; r5-proven cheap).
// x2 contracted-FMA chain (matches XLA:CPU fused codegen); dot(i,i) == x2(i)
// bit-exact => D[i,i] == 0 exactly.
// ---------------------------------------------------------------------------
__global__ __launch_bounds__(256) void prep_kernel(const float* __restrict__ X,
                                                   const float* __restrict__ mask,
                                                   float4* __restrict__ c4,
                                                   int* __restrict__ nvalid) {
#pragma clang fp contract(off)
    int i = blockIdx.x * 256 + threadIdx.x;              // i in [0, B*L)
    const float4* X4 = (const float4*)X;                 // residue = 3 aligned float4
    float4 a = X4[3 * i];                                // ... f3(=CA x)
    float4 bb = X4[3 * i + 1];                           // f4(=CA y) f5(=CA z) ...
    float x = a.w, y = bb.x, z = bb.y;
    float x2 = __builtin_fmaf(z, z, __builtin_fmaf(y, y, x * x));
    float m = mask[i];
    c4[i] = make_float4(x, y, z, (m > 0.0f) ? x2 : INVALID_X2);
    unsigned long long bal = __ballot(m > 0.0f);
    if ((threadIdx.x & 63) == 0)
        atomicAdd(&nvalid[i >> 12], (int)__popcll(bal));  // block spans one batch
}

// full ascending 64-lane bitonic sort; returns this lane's sorted value
__device__ __forceinline__ unsigned wave_sort64(unsigned sv, int lane) {
#pragma unroll
    for (int k = 2; k <= 64; k <<= 1) {
#pragma unroll
        for (int j = k >> 1; j > 0; j >>= 1) {
            unsigned o = __shfl_xor(sv, j);
            unsigned mn = min(sv, o), mx = max(sv, o);
            bool asc = ((lane & k) == 0);
            bool low = ((lane & j) == 0);
            sv = (asc == low) ? mn : mx;
        }
    }
    return sv;
}

// ---------------------------------------------------------------------------
// main: one block per 2 consecutive rows (same batch), 256 threads.
//  A:  load 16 candidates ONCE; d^2 for BOTH rows via packed v2f fma chain
//      (v_pk_fma_f32: bit-identical per half to scalar); per-row min in v2f.
//  B:  certified tight threshold per row = EXACT 48th-smallest of the 256
//      thread-minima (<=47 elements < q48 => <=47 minima < q48 => 48th
//      minimum >= q48). Per-wave bitonic sort -> (val,id) lists in LDS ->
//      co-rank of first 48 of each list; rank-47 publishes T.
//  C:  compact survivors (d2 <= T+SLACK in float domain, monotone for >=0),
//      storing EXACT key (sqrt_bits<<32|j) at push time.
//  D:  rank-count in (sqrt_bits, idx) order == lax.top_k tie-break, scatter;
//      invalid row -> self-fill. All cross-stage LDS deps barriered (3 total).
// ---------------------------------------------------------------------------
__global__ __launch_bounds__(NT) void knn_kernel(const float4* __restrict__ c4,
                                                 const int* __restrict__ nvalid,
                                                 float* __restrict__ dn,
                                                 float* __restrict__ ei) {
    __shared__ u64 smin[ROWS][NT];      // 4 KB: sorted minima (composite keys)
    __shared__ u64 surv[ROWS][CAP];     // 8 KB
    __shared__ int cnt[ROWS];
    __shared__ unsigned Tsh[ROWS];

    const int row0 = blockIdx.x * ROWS;
    const int b = row0 >> 12;
    const int i0 = row0 & (L_DIM - 1);
    const int t = threadIdx.x;
    const int w = t >> 6, lane = t & 63;

    // degenerate batch -> both rows self-fill (block-uniform)
    if (nvalid[b] <= KNN) {
        if (w < ROWS && lane < KNN) {
            dn[(size_t)(row0 + w) * KNN + lane] = 0.0f;
            ei[(size_t)(row0 + w) * KNN + lane] = (float)(i0 + w);
        }
        return;
    }

    const float4* cb = c4 + (size_t)b * L_DIM;
    const float4 q0 = cb[i0];                  // broadcast loads
    const float4 q1 = cb[i0 + 1];
    const bool v0 = (q0.w < VALID_TH), v1 = (q1.w < VALID_TH);
    const v2f qx = {q0.x, q1.x}, qy = {q0.y, q1.y},
              qz = {q0.z, q1.z}, qw = {q0.w, q1.w};
    const v2f m2 = {-2.0f, -2.0f}, zero2 = {0.0f, 0.0f};

    // ---- A: 16 candidates/thread, packed d^2 for both rows ----
    v2f d2v[CPT];
    v2f rmin2 = {3.402823466e38f, 3.402823466e38f};
    {
#pragma clang fp contract(off)
#pragma unroll
        for (int c = 0; c < CPT; ++c) {
            int j = c * NT + t;
            float4 pj = cb[j];
            v2f px = {pj.x, pj.x}, py = {pj.y, pj.y},
                pz = {pj.z, pj.z}, pw = {pj.w, pj.w};
            // dot halves: fma(pj.z,q.z, fma(pj.y,q.y, pj.x*q.x)) per row
            v2f dot = vfma2(pz, qz, vfma2(py, qy, px * qx));
            v2f t1 = qw + pw;                  // (x2_i + x2_j) per row, 1 rounding
            // fma(-2,dot,t1) == (t1 - 2*dot) bit-exact (2*dot exact, 1 rounding)
            v2f d2 = vmax2(vfma2(m2, dot, t1), zero2);
            d2v[c] = d2;
            rmin2 = vmin2(rmin2, d2);          // nonneg: float min == bit min
        }
    }
    if (t < ROWS) cnt[t] = 0;

    // ---- B: sorted minima lists (composite (value<<32)|uniqueid) ----
    {
        unsigned sv0 = wave_sort64(__float_as_uint(rmin2.x), lane);
        unsigned sv1 = wave_sort64(__float_as_uint(rmin2.y), lane);
        smin[0][t] = ((u64)sv0 << 32) | (unsigned)t;   // ascending per wave seg
        smin[1][t] = ((u64)sv1 << 32) | (unsigned)t;
    }
    __syncthreads();                                   // S2

    // co-rank: candidates = first KNN of each wave's sorted list, both rows
    for (int tau = t; tau < ROWS * NW * KNN; tau += NT) {
        int r = tau / (NW * KNN);
        int rest = tau - r * (NW * KNN);
        int ww = rest / KNN, p = rest - ww * KNN;
        u64 key = smin[r][ww * 64 + p];
        int grank = p;                          // elements before it in own list
#pragma unroll
        for (int w2 = 0; w2 < NW; ++w2) {
            if (w2 == ww) continue;
            const u64* arr = &smin[r][w2 * 64];
            int lo = 0;
#pragma unroll
            for (int s = 32; s >= 1; s >>= 1)
                if (arr[lo + s - 1] < key) lo += s;
            lo += (arr[lo] < key) ? 1 : 0;      // lo in [0,64] = count < key
            grank += lo;
        }
        if (grank == KNN - 1) Tsh[r] = (unsigned)(key >> 32);  // unique publisher
    }
    __syncthreads();                                   // S3
    // float-domain thresholds (monotone for nonneg); invalid row: -1 => none
    const float Tf0 = v0 ? __uint_as_float(Tsh[0] + SLACK) : -1.0f;
    const float Tf1 = v1 ? __uint_as_float(Tsh[1] + SLACK) : -1.0f;

    // ---- C: compact survivors per row, exact sqrt key at push time ----
#pragma unroll
    for (int c = 0; c < CPT; ++c) {
        unsigned j = (unsigned)(c * NT + t);
        if (d2v[c].x <= Tf0) {
            int pos = atomicAdd(&cnt[0], 1);
            if (pos < CAP) {
                float d = sqrtf(d2v[c].x);             // correctly rounded
                surv[0][pos] = ((u64)__float_as_uint(d) << 32) | j;
            }
        }
        if (d2v[c].y <= Tf1) {
            int pos = atomicAdd(&cnt[1], 1);
            if (pos < CAP) {
                float d = sqrtf(d2v[c].y);
                surv[1][pos] = ((u64)__float_as_uint(d) << 32) | j;
            }
        }
    }
    __syncthreads();                                   // S4

    // ---- D: per row, block-wide exact rank + scatter (or self-fill) ----
#pragma unroll
    for (int r = 0; r < ROWS; ++r) {
        const bool vr = r ? v1 : v0;
        float* dnrow = dn + (size_t)(row0 + r) * KNN;
        float* eirow = ei + (size_t)(row0 + r) * KNN;
        if (!vr) {                              // block-uniform branch
            if (t < KNN) { dnrow[t] = 0.0f; eirow[t] = (float)(i0 + r); }
        } else {
            int S = cnt[r]; if (S > CAP) S = CAP;
            for (int c = t; c < S; c += NT) {
                u64 key = surv[r][c];
                int rank = 0;
                for (int s = 0; s < S; ++s) rank += (surv[r][s] < key);  // bcast
                if (rank < KNN) {
                    dnrow[rank] = __uint_as_float((unsigned)(key >> 32));
                    eirow[rank] = (float)(key & 0xFFFFFFFFULL);
                }
            }
        }
    }
}

extern "C" void kernel_launch(void* const* d_in, const int* in_sizes, int n_in,
                              void* d_out, int out_size, void* d_ws, size_t ws_size,
                              hipStream_t stream) {
    const float* X = (const float*)d_in[0];
    const float* mask = (const float*)d_in[1];

    float* out = (float*)d_out;
    float* dn = out;                                   // (B,L,K) D_neighbors
    float* ei = out + (size_t)B_DIM * L_DIM * KNN;     // (B,L,K) E_idx as f32

    char* ws = (char*)d_ws;
    float4* c4 = (float4*)ws;                          // 256 KiB
    int* nv = (int*)(ws + (size_t)B_DIM * L_DIM * 16);

    hipMemsetAsync(nv, 0, B_DIM * sizeof(int), stream);
    prep_kernel<<<(B_DIM * L_DIM) / 256, 256, 0, stream>>>(X, mask, c4, nv);
    knn_kernel<<<(B_DIM * L_DIM) / ROWS, NT, 0, stream>>>(c4, nv, dn, ei);
}

// Round 14
// 72.090 us; speedup vs baseline: 1.6004x; 1.2680x over previous
//
#include <hip/hip_runtime.h>

typedef unsigned long long u64;

#define L_DIM 4096
#define B_DIM 4
#define KNN 48
#define CAP 512             // survivors/row ~88 expected (F~2.1%); 5.8x margin
#define INVALID_X2 1.0e30f  // encodes mask=0: d^2 ~ 1e30, never selectable
#define VALID_TH 1.0e29f
#define SLACK 8u            // ulp slack on d^2 threshold covering sqrt collisions
#define NT 256
#define NW 4
#define CPT 16              // candidates per thread (NT*CPT = L_DIM)
#define ROWS 2              // query rows per block (same batch; candidates shared)

// ---------------------------------------------------------------------------
// prep: c4 = (x, y, z, valid ? x2 : 1e30); per-batch n_valid via one ballot +
// lane0 atomic per wave (single-address, coalesced-friendly).
// x2 contracted-FMA chain (matches XLA:CPU fused codegen); dot(i,i) == x2(i)
// bit-exact => D[i,i] == 0 exactly.
// ---------------------------------------------------------------------------
__global__ __launch_bounds__(256) void prep_kernel(const float* __restrict__ X,
                                                   const float* __restrict__ mask,
                                                   float4* __restrict__ c4,
                                                   int* __restrict__ nvalid) {
#pragma clang fp contract(off)
    int i = blockIdx.x * 256 + threadIdx.x;              // i in [0, B*L)
    const float4* X4 = (const float4*)X;                 // residue = 3 aligned float4
    float4 a = X4[3 * i];                                // ... f3(=CA x)
    float4 bb = X4[3 * i + 1];                           // f4(=CA y) f5(=CA z) ...
    float x = a.w, y = bb.x, z = bb.y;
    float x2 = __builtin_fmaf(z, z, __builtin_fmaf(y, y, x * x));
    float m = mask[i];
    c4[i] = make_float4(x, y, z, (m > 0.0f) ? x2 : INVALID_X2);
    unsigned long long bal = __ballot(m > 0.0f);
    if ((threadIdx.x & 63) == 0)
        atomicAdd(&nvalid[i >> 12], (int)__popcll(bal));  // block spans one batch
}

// full ascending 64-lane bitonic sort; returns this lane's sorted value
__device__ __forceinline__ unsigned wave_sort64(unsigned sv, int lane) {
#pragma unroll
    for (int k = 2; k <= 64; k <<= 1) {
#pragma unroll
        for (int j = k >> 1; j > 0; j >>= 1) {
            unsigned o = __shfl_xor(sv, j);
            unsigned mn = min(sv, o), mx = max(sv, o);
            bool asc = ((lane & k) == 0);
            bool low = ((lane & j) == 0);
            sv = (asc == low) ? mn : mx;
        }
    }
    return sv;
}

// ---------------------------------------------------------------------------
// main: one block per 2 consecutive rows (same batch), 256 threads.
//  A:  load 16 candidates ONCE; d^2 bits for BOTH rows; per-row per-thread min.
//  B:  2-level certified threshold: group-of-4 minima (2 chained shfl_xor)
//      -> 64 group-minima/row in LDS -> ONE wave-sort per row (waves 0/1 in
//      parallel); lane 47 publishes T = 48th-smallest group-min.
//      Cert: each group-min covers 64 candidates; <=47 elements < q48 =>
//      <=47 group-minima < q48 => 48th group-min >= q48.
//      Tightness: 1-(1-F)^64 = 48/64 => F~2.1% => S~88.
//  C:  compact survivors (d2 <= T+SLACK bit-domain), exact sqrt key at push.
//  D:  rank-count in (sqrt_bits, idx) order == lax.top_k tie-break, scatter;
//      invalid row -> self-fill. All cross-stage LDS deps barriered (3 total).
// ---------------------------------------------------------------------------
__global__ __launch_bounds__(NT) void knn_kernel(const float4* __restrict__ c4,
                                                 const int* __restrict__ nvalid,
                                                 float* __restrict__ dn,
                                                 float* __restrict__ ei) {
    __shared__ unsigned gmin[ROWS][64];  // 512 B: group-of-4 minima
    __shared__ u64 surv[ROWS][CAP];      // 8 KB
    __shared__ int cnt[ROWS];
    __shared__ unsigned Tsh[ROWS];

    const int row0 = blockIdx.x * ROWS;
    const int b = row0 >> 12;
    const int i0 = row0 & (L_DIM - 1);
    const int t = threadIdx.x;
    const int w = t >> 6, lane = t & 63;

    // degenerate batch -> both rows self-fill (block-uniform)
    if (nvalid[b] <= KNN) {
        if (w < ROWS && lane < KNN) {
            dn[(size_t)(row0 + w) * KNN + lane] = 0.0f;
            ei[(size_t)(row0 + w) * KNN + lane] = (float)(i0 + w);
        }
        return;
    }

    const float4* cb = c4 + (size_t)b * L_DIM;
    const float4 q0 = cb[i0];                  // broadcast loads
    const float4 q1 = cb[i0 + 1];
    const bool v0 = (q0.w < VALID_TH), v1 = (q1.w < VALID_TH);

    // ---- A: 16 candidates/thread, d^2 for both rows ----
    unsigned d20[CPT], d21[CPT];
    unsigned rmin0 = 0xFFFFFFFFu, rmin1 = 0xFFFFFFFFu;
    {
#pragma clang fp contract(off)
#pragma unroll
        for (int c = 0; c < CPT; ++c) {
            int j = c * NT + t;
            float4 pj = cb[j];
            float dota = __builtin_fmaf(pj.z, q0.z,
                         __builtin_fmaf(pj.y, q0.y, pj.x * q0.x));
            float dotb = __builtin_fmaf(pj.z, q1.z,
                         __builtin_fmaf(pj.y, q1.y, pj.x * q1.x));
            // fma(-2,dot,t1) == (t1 - 2*dot) bit-exactly (2*dot exact, 1 rounding)
            float d2a = fmaxf(__builtin_fmaf(-2.0f, dota, q0.w + pj.w), 0.0f);
            float d2b = fmaxf(__builtin_fmaf(-2.0f, dotb, q1.w + pj.w), 0.0f);
            d20[c] = __float_as_uint(d2a);
            d21[c] = __float_as_uint(d2b);
            rmin0 = min(rmin0, d20[c]);
            rmin1 = min(rmin1, d21[c]);
        }
    }

    // ---- B: group-of-4 minima -> one wave-sort per row ----
    {
        unsigned g0 = min(rmin0, __shfl_xor(rmin0, 1));
        g0 = min(g0, __shfl_xor(g0, 2));
        unsigned g1 = min(rmin1, __shfl_xor(rmin1, 1));
        g1 = min(g1, __shfl_xor(g1, 2));
        if ((lane & 3) == 0) {
            gmin[0][(w << 4) | (lane >> 2)] = g0;
            gmin[1][(w << 4) | (lane >> 2)] = g1;
        }
    }
    if (t < ROWS) cnt[t] = 0;
    __syncthreads();                                   // S1
    if (w < ROWS) {
        unsigned sv = wave_sort64(gmin[w][lane], lane);
        if (lane == KNN - 1) Tsh[w] = sv;              // 48th-smallest group-min
    }
    __syncthreads();                                   // S2
    const unsigned Tp0 = v0 ? (Tsh[0] + SLACK) : 0u;   // invalid row: no survivors
    const unsigned Tp1 = v1 ? (Tsh[1] + SLACK) : 0u;

    // ---- C: compact survivors per row, exact sqrt key at push time ----
#pragma unroll
    for (int c = 0; c < CPT; ++c) {
        unsigned j = (unsigned)(c * NT + t);
        if (d20[c] <= Tp0) {
            int pos = atomicAdd(&cnt[0], 1);
            if (pos < CAP) {
                float d = sqrtf(__uint_as_float(d20[c]));   // correctly rounded
                surv[0][pos] = ((u64)__float_as_uint(d) << 32) | j;
            }
        }
        if (d21[c] <= Tp1) {
            int pos = atomicAdd(&cnt[1], 1);
            if (pos < CAP) {
                float d = sqrtf(__uint_as_float(d21[c]));
                surv[1][pos] = ((u64)__float_as_uint(d) << 32) | j;
            }
        }
    }
    __syncthreads();                                   // S3

    // ---- D: per row, block-wide exact rank + scatter (or self-fill) ----
#pragma unroll
    for (int r = 0; r < ROWS; ++r) {
        const bool vr = r ? v1 : v0;
        float* dnrow = dn + (size_t)(row0 + r) * KNN;
        float* eirow = ei + (size_t)(row0 + r) * KNN;
        if (!vr) {                              // block-uniform branch
            if (t < KNN) { dnrow[t] = 0.0f; eirow[t] = (float)(i0 + r); }
        } else {
            int S = cnt[r]; if (S > CAP) S = CAP;
            for (int c = t; c < S; c += NT) {
                u64 key = surv[r][c];
                int rank = 0;
                for (int s = 0; s < S; ++s) rank += (surv[r][s] < key);  // bcast
                if (rank < KNN) {
                    dnrow[rank] = __uint_as_float((unsigned)(key >> 32));
                    eirow[rank] = (float)(key & 0xFFFFFFFFULL);
                }
            }
        }
    }
}

extern "C" void kernel_launch(void* const* d_in, const int* in_sizes, int n_in,
                              void* d_out, int out_size, void* d_ws, size_t ws_size,
                              hipStream_t stream) {
    const float* X = (const float*)d_in[0];
    const float* mask = (const float*)d_in[1];

    float* out = (float*)d_out;
    float* dn = out;                                   // (B,L,K) D_neighbors
    float* ei = out + (size_t)B_DIM * L_DIM * KNN;     // (B,L,K) E_idx as f32

    char* ws = (char*)d_ws;
    float4* c4 = (float4*)ws;                          // 256 KiB
    int* nv = (int*)(ws + (size_t)B_DIM * L_DIM * 16);

    hipMemsetAsync(nv, 0, B_DIM * sizeof(int), stream);
    prep_kernel<<<(B_DIM * L_DIM) / 256, 256, 0, stream>>>(X, mask, c4, nv);
    knn_kernel<<<(B_DIM * L_DIM) / ROWS, NT, 0, stream>>>(c4, nv, dn, ei);
}